// Round 16
// baseline (1022.839 us; speedup 1.0000x reference)
//
#include <hip/hip_runtime.h>
#include <stdint.h>
#include <stdio.h>

#define NOUT 512
#define NSEG 1024

typedef unsigned short u16;
typedef __attribute__((ext_vector_type(4))) float f32x4;
typedef __attribute__((ext_vector_type(8))) short s16x8;
typedef __attribute__((ext_vector_type(4))) unsigned short u16x4;

__device__ __forceinline__ u16 f2b(float f) {
  union { float f; uint32_t u; } v; v.f = f;
  uint32_t r = v.u + 0x7FFFu + ((v.u >> 16) & 1u);
  return (u16)(r >> 16);
}
__device__ __forceinline__ float b2f(u16 b) {
  union { uint32_t u; float f; } v; v.u = ((uint32_t)b) << 16;
  return v.f;
}

typedef __attribute__((address_space(1))) const void GAS;
typedef __attribute__((address_space(3))) void LAS;
__device__ __forceinline__ void llds16(const void* g, void* l) {
  __builtin_amdgcn_global_load_lds((GAS*)g, (LAS*)l, 16, 0, 0);
}

// ---------------- fused input casts (x and dist in one launch) ----------------
__global__ void k_cast2(const float* __restrict__ x, u16* __restrict__ xb, long n4x,
                        const float* __restrict__ d, u16* __restrict__ db, long n4d) {
  long i0 = blockIdx.x * (long)blockDim.x + threadIdx.x;
  long stride = (long)gridDim.x * blockDim.x;
  for (long i = i0; i < n4x; i += stride) {
    float4 v = reinterpret_cast<const float4*>(x)[i];
    u16x4 o;
    o.x = f2b(v.x); o.y = f2b(v.y); o.z = f2b(v.z); o.w = f2b(v.w);
    reinterpret_cast<u16x4*>(xb)[i] = o;
  }
  for (long i = i0; i < n4d; i += stride) {
    float4 v = reinterpret_cast<const float4*>(d)[i];
    u16x4 o;
    o.x = f2b(v.x); o.y = f2b(v.y); o.z = f2b(v.z); o.w = f2b(v.w);
    reinterpret_cast<u16x4*>(db)[i] = o;
  }
}

// All three weight transposes in one launch: z selects {l1w,l2w,fw}.
__global__ void k_wtcastT3(const float* __restrict__ w0, u16* __restrict__ o0,
                           const float* __restrict__ w1, u16* __restrict__ o1,
                           const float* __restrict__ w2, u16* __restrict__ o2) {
  __shared__ float tile[32][33];
  int z = blockIdx.z;
  const float* w = z == 0 ? w0 : (z == 1 ? w1 : w2);
  u16* out = z == 0 ? o0 : (z == 1 ? o1 : o2);
  int K = z == 2 ? 1024 : 1280;
  int k0 = blockIdx.x * 32, c0 = blockIdx.y * 32;
  if (k0 >= K) return;
  int t = threadIdx.x;  // 256
  int rr = t >> 5, cc = t & 31;
#pragma unroll
  for (int p = 0; p < 4; ++p)
    tile[p * 8 + rr][cc] = w[(long)(k0 + p * 8 + rr) * NOUT + c0 + cc];
  __syncthreads();
#pragma unroll
  for (int p = 0; p < 4; ++p)
    out[(long)(c0 + p * 8 + rr) * K + k0 + cc] = f2b(tile[cc][p * 8 + rr]);
}

// ---------------- segment sort ----------------
__global__ void k_hist(const int* __restrict__ ele, int* __restrict__ cnt, int N) {
  int i = blockIdx.x * blockDim.x + threadIdx.x;
  int stride = gridDim.x * blockDim.x;
  for (; i < N; i += stride) atomicAdd(&cnt[ele[i]], 1);
}

__global__ void k_scan(const int* __restrict__ cnt, int* __restrict__ off) {
  __shared__ int tmp[NSEG];
  int t = threadIdx.x;
  tmp[t] = cnt[t];
  __syncthreads();
  for (int o = 1; o < NSEG; o <<= 1) {
    int add = (t >= o) ? tmp[t - o] : 0;
    __syncthreads();
    tmp[t] += add;
    __syncthreads();
  }
  off[t] = tmp[t] - cnt[t];
}

__global__ void k_scatter(const int* __restrict__ ele, const int* __restrict__ off,
                          int* __restrict__ fill, int* __restrict__ rows, int N) {
  int i = blockIdx.x * blockDim.x + threadIdx.x;
  int stride = gridDim.x * blockDim.x;
  for (; i < N; i += stride) {
    int e = ele[i];
    int p = atomicAdd(&fill[e], 1);
    rows[off[e] + p] = i;
  }
}

// ---------------- fused BN-finalize + apply + ReLU + segment mean ----------------
__global__ void k_bnseg(const u16* __restrict__ hp, u16* __restrict__ h, u16* __restrict__ mean,
                        const float* __restrict__ stats, const float* __restrict__ g,
                        const float* __restrict__ be, float invM,
                        const int* __restrict__ off, const int* __restrict__ cnt,
                        const int* __restrict__ rows) {
  int s = blockIdx.x;
  int c0 = 2 * threadIdx.x;  // 256 threads -> cols c0, c0+1
  int n = cnt[s], o = off[s];
  float m0 = stats[c0] * invM, m1 = stats[c0 + 1] * invM;
  float v0 = stats[NOUT + c0] * invM - m0 * m0;
  float v1 = stats[NOUT + c0 + 1] * invM - m1 * m1;
  float a0 = g[c0] * rsqrtf(v0 + 1e-5f);
  float a1 = g[c0 + 1] * rsqrtf(v1 + 1e-5f);
  float cc0 = be[c0] - a0 * m0;
  float cc1 = be[c0 + 1] - a1 * m1;
  float s0 = 0.f, s1 = 0.f;
#pragma unroll 2
  for (int j = 0; j < n; ++j) {
    int r = rows[o + j];
    uint32_t v = *reinterpret_cast<const uint32_t*>(&hp[(long)r * NOUT + c0]);
    float h0 = fmaxf(a0 * b2f((u16)(v & 0xffff)) + cc0, 0.f);
    float h1 = fmaxf(a1 * b2f((u16)(v >> 16)) + cc1, 0.f);
    s0 += h0; s1 += h1;
    *reinterpret_cast<uint32_t*>(&h[(long)r * NOUT + c0]) =
        ((uint32_t)f2b(h1) << 16) | (uint32_t)f2b(h0);
  }
  float inv = 1.f / fmaxf((float)n, 1.f);
  *reinterpret_cast<uint32_t*>(&mean[(long)s * NOUT + c0]) =
      ((uint32_t)f2b(s1 * inv) << 16) | (uint32_t)f2b(s0 * inv);
}

// ---------------- final BN+ReLU to f32 out; finalize once per block into LDS ----------------
__global__ void k_final(const u16* __restrict__ hp, float* __restrict__ out,
                        const float* __restrict__ stats, const float* __restrict__ g,
                        const float* __restrict__ be, float invM, long n4) {
  __shared__ float sA[NOUT], sC[NOUT];
  for (int c = threadIdx.x; c < NOUT; c += blockDim.x) {
    float m = stats[c] * invM;
    float v = stats[NOUT + c] * invM - m * m;
    float a = g[c] * rsqrtf(v + 1e-5f);
    sA[c] = a;
    sC[c] = be[c] - a * m;
  }
  __syncthreads();
  long i = blockIdx.x * (long)blockDim.x + threadIdx.x;
  long stride = (long)gridDim.x * blockDim.x;
  for (; i < n4; i += stride) {
    u16x4 v = reinterpret_cast<const u16x4*>(hp)[i];
    int c0 = (int)((i * 4) & (NOUT - 1));
    float4 a = *reinterpret_cast<const float4*>(&sA[c0]);
    float4 c = *reinterpret_cast<const float4*>(&sC[c0]);
    float4 o;
    o.x = fmaxf(a.x * b2f(v.x) + c.x, 0.f);
    o.y = fmaxf(a.y * b2f(v.y) + c.y, 0.f);
    o.z = fmaxf(a.z * b2f(v.z) + c.z, 0.f);
    o.w = fmaxf(a.w * b2f(v.w) + c.w, 0.f);
    reinterpret_cast<float4*>(out)[i] = o;
  }
}

// ---------------- GEMM: C[M,512] = A[M,K] @ W[K,512] ----------------
// R15 2-phase loop, tile grown to BM=192 x BN=128 (acc[6][4] = 96): 24 MFMA per
// wave per barrier-phase (+50% barrier amortization), LDS 40KB dual-buffer ->
// 3 blocks/CU. Same phase order / swizzle algebra as R13/R15 (all row offsets
// multiple of 16 so (row>>1)&3 folds to identical lane expressions).
// Staging: chunk c covers rows 16c..16c+15; A chunks = wid*3+i (12), B = wid*2+i
// (8); lane writes LDS row 16c+(lane>>2), octet lane&3; source octet
// (lane&3)^((lane>>3)&3)  [= (lane&3)^((row>>1)&3)].
// Tripwire: WRITE_SIZE must stay ~106MB (spill shows as GBs); epilogue reads acc
// SCALAR-wise only. A: 2 regions (k<E0 -> p0 gather?g0 else p1 gather?g1).
// B: wbt [512][ldb] (=W^T), k += BSKIP when k>=E0B. Biases dropped (cancel in BN).
template <int K, int E0, int E0B, int BSKIP>
__global__ __launch_bounds__(256, 3) void k_gemm(
    const u16* p0, const u16* p1, int w0, int w1, int g0, int g1,
    const int* __restrict__ ele,
    const u16* __restrict__ wbt, int ldb,
    const float* __restrict__ tab, int addtab,
    u16* __restrict__ outp, float* __restrict__ outf, int wf32,
    float* __restrict__ csum, float* __restrict__ csq, int dostats,
    int M) {
  __shared__ __align__(16) u16 As[2 * 6144];  // 2 x [192][32]
  __shared__ __align__(16) u16 Bs[2 * 4096];  // 2 x [128][32]

  int nwg = gridDim.x;
  int orig = blockIdx.x;
  // bijective XCD swizzle (m204)
  int q = nwg >> 3, r8 = nwg & 7;
  int xcd = orig & 7, loc = orig >> 3;
  int bid = (xcd < r8 ? xcd * (q + 1) : r8 * (q + 1) + (xcd - r8) * q) + loc;
  int mt = bid >> 2, ct = bid & 3;  // 4 col-tiles of same mt adjacent -> L2 A reuse
  int brow = mt * 192, bcol = ct * 128;

  int tid = (int)threadIdx.x;
  int lane = tid & 63;
  int wid = tid >> 6;
  int wr = wid >> 1, wc = wid & 1;  // 2x2 waves; per-wave 96x64
  int l15 = lane & 15, kg = lane >> 4;

  // staging lane geometry: row-in-chunk = lane>>2, octet slot = lane&3,
  // source octet = (lane&3)^((lane>>3)&3)
  int lrow = lane >> 2;
  int lsoct = ((lane & 3) ^ ((lane >> 3) & 3)) * 8;

  // A: 3 chunks/thread (chunk = wid*3+i), rows 16*chunk + lrow
  const u16 *a0p[3], *a1p[3];
#pragma unroll
  for (int i = 0; i < 3; ++i) {
    int gr = brow + 16 * (wid * 3 + i) + lrow;
    if (gr >= M) gr = M - 1;
    int e = (g0 | g1) ? ele[gr] : 0;
    a0p[i] = p0 + (long)(g0 ? e : gr) * w0 + lsoct;
    a1p[i] = p1 + (long)(g1 ? e : gr) * w1 + lsoct - E0;
  }
  // B: 2 chunks/thread (chunk = wid*2+i), cols 16*chunk + lrow (< 512)
  const u16* bp[2];
#pragma unroll
  for (int i = 0; i < 2; ++i)
    bp[i] = wbt + (long)(bcol + 16 * (wid * 2 + i) + lrow) * ldb + lsoct;

  // swizzled fragment-read offsets (u16 index within one buffer)
  int xoct = (kg ^ ((l15 >> 1) & 3)) * 8;
  int aro = (wr * 96 + l15) * 32 + xoct;
  int bro = (wc * 64 + l15) * 32 + xoct;

  f32x4 acc[6][4];
#pragma unroll
  for (int m = 0; m < 6; ++m)
#pragma unroll
    for (int n = 0; n < 4; ++n)
#pragma unroll
      for (int j = 0; j < 4; ++j) acc[m][n][j] = 0.f;

  constexpr int KT = K >> 5;

  auto stage = [&](int tt, int buf) {
    int k0 = tt << 5;
    int bo = k0 + (k0 >= E0B ? BSKIP : 0);
    if (k0 < E0) {
#pragma unroll
      for (int i = 0; i < 3; ++i)
        llds16(a0p[i] + k0, &As[buf * 6144 + (wid * 3 + i) * 512]);
    } else {
#pragma unroll
      for (int i = 0; i < 3; ++i)
        llds16(a1p[i] + k0, &As[buf * 6144 + (wid * 3 + i) * 512]);
    }
#pragma unroll
    for (int i = 0; i < 2; ++i)
      llds16(bp[i] + bo, &Bs[buf * 4096 + (wid * 2 + i) * 512]);
  };

  stage(0, 0);
  __syncthreads();

#pragma unroll
  for (int t = 0; t < KT; ++t) {
    int cur = t & 1;
    if (t + 1 < KT) stage(t + 1, cur ^ 1);
    __builtin_amdgcn_sched_barrier(0);
    const u16* Ab = &As[cur * 6144];
    const u16* Bb = &Bs[cur * 4096];
    s16x8 af[6], bf[4];
#pragma unroll
    for (int m = 0; m < 6; ++m)
      af[m] = *reinterpret_cast<const s16x8*>(&Ab[m * 512 + aro]);
#pragma unroll
    for (int n = 0; n < 4; ++n)
      bf[n] = *reinterpret_cast<const s16x8*>(&Bb[n * 512 + bro]);
#pragma unroll
    for (int m = 0; m < 6; ++m)
#pragma unroll
      for (int n = 0; n < 4; ++n)
        acc[m][n] = __builtin_amdgcn_mfma_f32_16x16x32_bf16(af[m], bf[n], acc[m][n], 0, 0, 0);
    __syncthreads();  // drain after MFMA: next-tile loads had the full phase to land
  }

  // epilogue: C layout col = lane&15, row = kg*4+j (m89-verified); scalar acc reads only
  float sums[4] = {0.f, 0.f, 0.f, 0.f}, sqs[4] = {0.f, 0.f, 0.f, 0.f};
#pragma unroll
  for (int m = 0; m < 6; ++m) {
    int row0 = brow + wr * 96 + m * 16 + kg * 4;
#pragma unroll
    for (int j = 0; j < 4; ++j) {
      int r = row0 + j;
      if (r < M) {
        long rb = (long)r * NOUT;
        long tb = addtab ? (long)ele[r] * NOUT : 0;
#pragma unroll
        for (int n = 0; n < 4; ++n) {
          int col = bcol + wc * 64 + n * 16 + l15;
          float v = acc[m][n][j];
          if (addtab) v += tab[tb + col];
          if (wf32) outf[rb + col] = v;
          else outp[rb + col] = f2b(v);
          sums[n] += v;
          sqs[n] += v * v;
        }
      }
    }
  }
  if (dostats) {
#pragma unroll
    for (int n = 0; n < 4; ++n) {
      sums[n] += __shfl_xor(sums[n], 16);
      sums[n] += __shfl_xor(sums[n], 32);
      sqs[n] += __shfl_xor(sqs[n], 16);
      sqs[n] += __shfl_xor(sqs[n], 32);
    }
    if (kg == 0) {
#pragma unroll
      for (int n = 0; n < 4; ++n) {
        int col = bcol + wc * 64 + n * 16 + l15;
        atomicAdd(&csum[col], sums[n]);
        atomicAdd(&csq[col], sqs[n]);
      }
    }
  }
}

// ---------------- host ----------------
extern "C" void kernel_launch(void* const* d_in, const int* in_sizes, int n_in,
                              void* d_out, int out_size, void* d_ws, size_t ws_size,
                              hipStream_t stream) {
  const float* x    = (const float*)d_in[0];
  const float* dist = (const float*)d_in[1];
  const int* ele    = (const int*)d_in[3];
  const float* l1w  = (const float*)d_in[4];
  const float* l1g  = (const float*)d_in[6];
  const float* l1be = (const float*)d_in[7];
  const float* l2w  = (const float*)d_in[8];
  const float* l2g  = (const float*)d_in[10];
  const float* l2be = (const float*)d_in[11];
  const float* fw   = (const float*)d_in[12];
  const float* fg   = (const float*)d_in[14];
  const float* fbe  = (const float*)d_in[15];

  int N = in_sizes[0] / 1024;  // 100000
  float* out = (float*)d_out;
  u16* xbf = (u16*)d_out;      // bf16 x overlays d_out (exact size, dead by final write)

  int MT = (N + 191) / 192;    // 521
  int mcMT = (NSEG + 191) / 192;  // 6

  char* w = (char*)d_ws;
  auto alloc = [&](size_t bytes) {
    char* p = w;
    w += (bytes + 255) & ~(size_t)255;
    return p;
  };
  u16* dist_bf = (u16*)alloc((size_t)N * 256 * 2);
  u16* hp      = (u16*)alloc((size_t)N * NOUT * 2);
  u16* h       = (u16*)alloc((size_t)N * NOUT * 2);
  u16* mean    = (u16*)alloc((size_t)NSEG * NOUT * 2);
  u16* w1bt    = (u16*)alloc((size_t)NOUT * 1280 * 2);
  u16* w2bt    = (u16*)alloc((size_t)NOUT * 1280 * 2);
  u16* fbt     = (u16*)alloc((size_t)NOUT * 1024 * 2);
  float* mc2   = (float*)alloc((size_t)NSEG * NOUT * 4);
  float* mc3   = (float*)alloc((size_t)NSEG * NOUT * 4);
  // ---- contiguous zero-zone: seg_cnt, seg_fill, stats1..3 (single memset) ----
  char* zz0    = w;
  int* seg_cnt = (int*)alloc(NSEG * 4);
  int* seg_fill = (int*)alloc(NSEG * 4);
  float* stats1 = (float*)alloc(NOUT * 2 * 4);  // [sum(512) | sumsq(512)]
  float* stats2 = (float*)alloc(NOUT * 2 * 4);
  float* stats3 = (float*)alloc(NOUT * 2 * 4);
  size_t zzlen = (size_t)(w - zz0);
  int* seg_off = (int*)alloc(NSEG * 4);
  int* rows    = (int*)alloc((size_t)N * 4);

  size_t need = (size_t)(w - (char*)d_ws);
  if (need > ws_size) {
    fprintf(stderr, "kernel_launch: ws too small: need %zu have %zu\n", need, ws_size);
    return;
  }

  long n4x = (long)N * 1024 / 4;
  long n4d = (long)N * 256 / 4;
  long n4h = (long)N * NOUT / 4;
  int gemmGrid = MT * 4;    // 2084
  int mcGrid = mcMT * 4;    // 24
  float invM = 1.0f / (float)N;

  // input casts + weight transposes + one zero-zone memset
  k_cast2<<<4096, 256, 0, stream>>>(x, xbf, n4x, dist, dist_bf, n4d);
  dim3 wtg(1280 / 32, NOUT / 32, 3);
  k_wtcastT3<<<wtg, 256, 0, stream>>>(l1w, w1bt, l2w, w2bt, fw, fbt);
  hipMemsetAsync(zz0, 0, zzlen, stream);

  // segment sort
  k_hist<<<512, 256, 0, stream>>>(ele, seg_cnt, N);
  k_scan<<<1, NSEG, 0, stream>>>(seg_cnt, seg_off);
  k_scatter<<<512, 256, 0, stream>>>(ele, seg_off, seg_fill, rows, N);

  // ---- layer 1: A = [x(1024) | dist(256)], K=1280 ----
  k_gemm<1280, 1024, 1280, 0><<<gemmGrid, 256, 0, stream>>>(
      xbf, dist_bf, 1024, 256, 0, 0, ele, w1bt, 1280, mc2, 0,
      hp, mc2, 0, stats1, stats1 + NOUT, 1, N);
  k_bnseg<<<NSEG, 256, 0, stream>>>(hp, h, mean, stats1, l1g, l1be, invM,
                                    seg_off, seg_cnt, rows);

  // ---- layer 2: mc2 = mean @ W2[512:1024); A = [h(512) | dist(256)], K=768 ----
  k_gemm<512, 512, 512, 0><<<mcGrid, 256, 0, stream>>>(
      mean, mean, 512, 512, 0, 0, ele, w2bt + 512, 1280, mc2, 0,
      hp, mc2, 1, stats2, stats2 + NOUT, 0, NSEG);
  k_gemm<768, 512, 512, 512><<<gemmGrid, 256, 0, stream>>>(
      h, dist_bf, 512, 256, 0, 0, ele, w2bt, 1280, mc2, 1,
      hp, mc2, 0, stats2, stats2 + NOUT, 1, N);
  k_bnseg<<<NSEG, 256, 0, stream>>>(hp, h, mean, stats2, l2g, l2be, invM,
                                    seg_off, seg_cnt, rows);

  // ---- final layer: mc3 = mean @ F[512:1024); A = h, K=512 ----
  k_gemm<512, 512, 512, 0><<<mcGrid, 256, 0, stream>>>(
      mean, mean, 512, 512, 0, 0, ele, fbt + 512, 1024, mc3, 0,
      hp, mc3, 1, stats3, stats3 + NOUT, 0, NSEG);
  k_gemm<512, 512, 512, 0><<<gemmGrid, 256, 0, stream>>>(
      h, h, 512, 512, 0, 0, ele, fbt, 1024, mc3, 1,
      hp, mc3, 0, stats3, stats3 + NOUT, 1, N);
  k_final<<<4096, 256, 0, stream>>>(hp, out, stats3, fg, fbe, invM, n4h);
}

// Round 17
// 909.144 us; speedup vs baseline: 1.1251x; 1.1251x over previous
//
#include <hip/hip_runtime.h>
#include <stdint.h>
#include <stdio.h>

#define NOUT 512
#define NSEG 1024

typedef unsigned short u16;
typedef __attribute__((ext_vector_type(4))) float f32x4;
typedef __attribute__((ext_vector_type(8))) short s16x8;
typedef __attribute__((ext_vector_type(4))) unsigned short u16x4;

__device__ __forceinline__ u16 f2b(float f) {
  union { float f; uint32_t u; } v; v.f = f;
  uint32_t r = v.u + 0x7FFFu + ((v.u >> 16) & 1u);
  return (u16)(r >> 16);
}
__device__ __forceinline__ float b2f(u16 b) {
  union { uint32_t u; float f; } v; v.u = ((uint32_t)b) << 16;
  return v.f;
}

typedef __attribute__((address_space(1))) const void GAS;
typedef __attribute__((address_space(3))) void LAS;
__device__ __forceinline__ void llds16(const void* g, void* l) {
  __builtin_amdgcn_global_load_lds((GAS*)g, (LAS*)l, 16, 0, 0);
}

// ---------------- fused input casts (x and dist in one launch) ----------------
__global__ void k_cast2(const float* __restrict__ x, u16* __restrict__ xb, long n4x,
                        const float* __restrict__ d, u16* __restrict__ db, long n4d) {
  long i0 = blockIdx.x * (long)blockDim.x + threadIdx.x;
  long stride = (long)gridDim.x * blockDim.x;
  for (long i = i0; i < n4x; i += stride) {
    float4 v = reinterpret_cast<const float4*>(x)[i];
    u16x4 o;
    o.x = f2b(v.x); o.y = f2b(v.y); o.z = f2b(v.z); o.w = f2b(v.w);
    reinterpret_cast<u16x4*>(xb)[i] = o;
  }
  for (long i = i0; i < n4d; i += stride) {
    float4 v = reinterpret_cast<const float4*>(d)[i];
    u16x4 o;
    o.x = f2b(v.x); o.y = f2b(v.y); o.z = f2b(v.z); o.w = f2b(v.w);
    reinterpret_cast<u16x4*>(db)[i] = o;
  }
}

// All three weight transposes in one launch: z selects {l1w,l2w,fw}.
// w: [K][512] f32 -> out: [512][K] bf16 (B^T), coalesced both sides via LDS tile.
__global__ void k_wtcastT3(const float* __restrict__ w0, u16* __restrict__ o0,
                           const float* __restrict__ w1, u16* __restrict__ o1,
                           const float* __restrict__ w2, u16* __restrict__ o2) {
  __shared__ float tile[32][33];
  int z = blockIdx.z;
  const float* w = z == 0 ? w0 : (z == 1 ? w1 : w2);
  u16* out = z == 0 ? o0 : (z == 1 ? o1 : o2);
  int K = z == 2 ? 1024 : 1280;
  int k0 = blockIdx.x * 32, c0 = blockIdx.y * 32;
  if (k0 >= K) return;
  int t = threadIdx.x;  // 256
  int rr = t >> 5, cc = t & 31;
#pragma unroll
  for (int p = 0; p < 4; ++p)
    tile[p * 8 + rr][cc] = w[(long)(k0 + p * 8 + rr) * NOUT + c0 + cc];
  __syncthreads();
#pragma unroll
  for (int p = 0; p < 4; ++p)
    out[(long)(c0 + p * 8 + rr) * K + k0 + cc] = f2b(tile[cc][p * 8 + rr]);
}

// ---------------- segment sort ----------------
__global__ void k_hist(const int* __restrict__ ele, int* __restrict__ cnt, int N) {
  int i = blockIdx.x * blockDim.x + threadIdx.x;
  int stride = gridDim.x * blockDim.x;
  for (; i < N; i += stride) atomicAdd(&cnt[ele[i]], 1);
}

__global__ void k_scan(const int* __restrict__ cnt, int* __restrict__ off) {
  __shared__ int tmp[NSEG];
  int t = threadIdx.x;
  tmp[t] = cnt[t];
  __syncthreads();
  for (int o = 1; o < NSEG; o <<= 1) {
    int add = (t >= o) ? tmp[t - o] : 0;
    __syncthreads();
    tmp[t] += add;
    __syncthreads();
  }
  off[t] = tmp[t] - cnt[t];
}

__global__ void k_scatter(const int* __restrict__ ele, const int* __restrict__ off,
                          int* __restrict__ fill, int* __restrict__ rows, int N) {
  int i = blockIdx.x * blockDim.x + threadIdx.x;
  int stride = gridDim.x * blockDim.x;
  for (; i < N; i += stride) {
    int e = ele[i];
    int p = atomicAdd(&fill[e], 1);
    rows[off[e] + p] = i;
  }
}

// ---------------- fused BN-finalize + apply + ReLU + segment mean ----------------
__global__ void k_bnseg(const u16* __restrict__ hp, u16* __restrict__ h, u16* __restrict__ mean,
                        const float* __restrict__ stats, const float* __restrict__ g,
                        const float* __restrict__ be, float invM,
                        const int* __restrict__ off, const int* __restrict__ cnt,
                        const int* __restrict__ rows) {
  int s = blockIdx.x;
  int c0 = 2 * threadIdx.x;  // 256 threads -> cols c0, c0+1
  int n = cnt[s], o = off[s];
  float m0 = stats[c0] * invM, m1 = stats[c0 + 1] * invM;
  float v0 = stats[NOUT + c0] * invM - m0 * m0;
  float v1 = stats[NOUT + c0 + 1] * invM - m1 * m1;
  float a0 = g[c0] * rsqrtf(v0 + 1e-5f);
  float a1 = g[c0 + 1] * rsqrtf(v1 + 1e-5f);
  float cc0 = be[c0] - a0 * m0;
  float cc1 = be[c0 + 1] - a1 * m1;
  float s0 = 0.f, s1 = 0.f;
#pragma unroll 2
  for (int j = 0; j < n; ++j) {
    int r = rows[o + j];
    uint32_t v = *reinterpret_cast<const uint32_t*>(&hp[(long)r * NOUT + c0]);
    float h0 = fmaxf(a0 * b2f((u16)(v & 0xffff)) + cc0, 0.f);
    float h1 = fmaxf(a1 * b2f((u16)(v >> 16)) + cc1, 0.f);
    s0 += h0; s1 += h1;
    *reinterpret_cast<uint32_t*>(&h[(long)r * NOUT + c0]) =
        ((uint32_t)f2b(h1) << 16) | (uint32_t)f2b(h0);
  }
  float inv = 1.f / fmaxf((float)n, 1.f);
  *reinterpret_cast<uint32_t*>(&mean[(long)s * NOUT + c0]) =
      ((uint32_t)f2b(s1 * inv) << 16) | (uint32_t)f2b(s0 * inv);
}

// ---------------- final BN+ReLU to f32 out; finalize once per block into LDS ----------------
__global__ void k_final(const u16* __restrict__ hp, float* __restrict__ out,
                        const float* __restrict__ stats, const float* __restrict__ g,
                        const float* __restrict__ be, float invM, long n4) {
  __shared__ float sA[NOUT], sC[NOUT];
  for (int c = threadIdx.x; c < NOUT; c += blockDim.x) {
    float m = stats[c] * invM;
    float v = stats[NOUT + c] * invM - m * m;
    float a = g[c] * rsqrtf(v + 1e-5f);
    sA[c] = a;
    sC[c] = be[c] - a * m;
  }
  __syncthreads();
  long i = blockIdx.x * (long)blockDim.x + threadIdx.x;
  long stride = (long)gridDim.x * blockDim.x;
  for (; i < n4; i += stride) {
    u16x4 v = reinterpret_cast<const u16x4*>(hp)[i];
    int c0 = (int)((i * 4) & (NOUT - 1));
    float4 a = *reinterpret_cast<const float4*>(&sA[c0]);
    float4 c = *reinterpret_cast<const float4*>(&sC[c0]);
    float4 o;
    o.x = fmaxf(a.x * b2f(v.x) + c.x, 0.f);
    o.y = fmaxf(a.y * b2f(v.y) + c.y, 0.f);
    o.z = fmaxf(a.z * b2f(v.z) + c.z, 0.f);
    o.w = fmaxf(a.w * b2f(v.w) + c.w, 0.f);
    reinterpret_cast<float4*>(out)[i] = o;
  }
}

// ---------------- GEMM: C[M,512] = A[M,K] @ W[K,512] ----------------
// R15-verbatim (best measured: 908us total; VGPR 56, acc in AGPRs, zero spill,
// MfmaUtil 23%, 0 bank conflicts). COMPILE-TIME K/E0/E0B/BSKIP fully unrolls the
// K-loop; region selects and B-offsets fold to immediates.
// 2-PHASE: dual 16KB LDS buffers; per K-tile: STAGE(buf^1, t+1) -> ds_read(cur)
// -> MFMA -> __syncthreads (vmcnt(0) drain lands AFTER compute).
// Tile 128x128, BK=32, 4 waves 2x2 (64x64 each), launch_bounds(256,4) -- measured
// optimum over 192x128 (R16: -12%) and 256x256 (R2: -20%).
// LDS [128][32] u16; conflict-free swizzle: 16B-chunk ^= (row>>1)&3, inverse-
// permuted GLOBAL source (m173) + XOR on ds_read (rule #21).
// NOTE: epilogue reads acc SCALAR-wise only (f32x4 copies of acc -> scratch spill).
// A: 2 regions (k<E0 -> p0 gather?g0 else p1 gather?g1). B: wbt [512][ldb] (=W^T),
// k += BSKIP when k>=E0B. Biases dropped (cancel in training-mode BN).
template <int K, int E0, int E0B, int BSKIP>
__global__ __launch_bounds__(256, 4) void k_gemm(
    const u16* p0, const u16* p1, int w0, int w1, int g0, int g1,
    const int* __restrict__ ele,
    const u16* __restrict__ wbt, int ldb,
    const float* __restrict__ tab, int addtab,
    u16* __restrict__ outp, float* __restrict__ outf, int wf32,
    float* __restrict__ csum, float* __restrict__ csq, int dostats,
    int M) {
  __shared__ __align__(16) u16 As[2 * 4096];
  __shared__ __align__(16) u16 Bs[2 * 4096];

  int nwg = gridDim.x;
  int orig = blockIdx.x;
  // bijective XCD swizzle (m204)
  int q = nwg >> 3, r8 = nwg & 7;
  int xcd = orig & 7, loc = orig >> 3;
  int bid = (xcd < r8 ? xcd * (q + 1) : r8 * (q + 1) + (xcd - r8) * q) + loc;
  int mt = bid >> 2, ct = bid & 3;  // 4 col-tiles of same mt adjacent -> L2 A reuse
  int brow = mt * 128, bcol = ct * 128;

  int tid = (int)threadIdx.x;
  int lane = tid & 63;
  int wid = tid >> 6;
  int wr = wid >> 1, wc = wid & 1;  // 2x2 waves, 64x64 each
  int l15 = lane & 15, kg = lane >> 4;

  // staging: thread t -> row srow(+64), chunk tid&3; source chunk inverse-swizzled
  int srow = tid >> 2;                             // 0..63
  int soct = ((tid & 3) ^ ((srow >> 1) & 3)) * 8;  // u16 source col-octet

  int gr0 = brow + srow, gr1 = gr0 + 64;
  int gr0c = gr0 < M ? gr0 : M - 1;
  int gr1c = gr1 < M ? gr1 : M - 1;
  int el0 = (g0 | g1) ? ele[gr0c] : 0, el1 = (g0 | g1) ? ele[gr1c] : 0;

  const u16* a00 = p0 + (long)(g0 ? el0 : gr0c) * w0 + soct;
  const u16* a01 = p1 + (long)(g1 ? el0 : gr0c) * w1 + soct - E0;
  const u16* a10 = p0 + (long)(g0 ? el1 : gr1c) * w0 + soct;
  const u16* a11 = p1 + (long)(g1 ? el1 : gr1c) * w1 + soct - E0;

  const u16* b0p = wbt + (long)(bcol + srow) * ldb + soct;        // cols < 512
  const u16* b1p = wbt + (long)(bcol + srow + 64) * ldb + soct;

  // swizzled fragment-read offsets (u16 index within one 4096-u16 buffer)
  int xoct = (kg ^ ((l15 >> 1) & 3)) * 8;
  int aro = (wr * 64 + l15) * 32 + xoct;
  int bro = (wc * 64 + l15) * 32 + xoct;

  f32x4 acc[4][4];
#pragma unroll
  for (int m = 0; m < 4; ++m)
#pragma unroll
    for (int n = 0; n < 4; ++n)
#pragma unroll
      for (int j = 0; j < 4; ++j) acc[m][n][j] = 0.f;

  constexpr int KT = K >> 5;
  int dst = wid * 512;  // u16: per-wave linear 1KB dest region

  auto stage = [&](int tt, int buf) {
    int k0 = tt << 5;
    const u16* sa0 = k0 < E0 ? a00 : a01;
    const u16* sa1 = k0 < E0 ? a10 : a11;
    int bo = k0 + (k0 >= E0B ? BSKIP : 0);
    int ab = buf * 4096 + dst;
    llds16(sa0 + k0, &As[ab]);
    llds16(sa1 + k0, &As[ab + 2048]);
    llds16(b0p + bo, &Bs[ab]);
    llds16(b1p + bo, &Bs[ab + 2048]);
  };

  stage(0, 0);
  __syncthreads();

#pragma unroll
  for (int t = 0; t < KT; ++t) {
    int cur = t & 1;
    if (t + 1 < KT) stage(t + 1, cur ^ 1);
    __builtin_amdgcn_sched_barrier(0);
    const u16* Ab = &As[cur * 4096];
    const u16* Bb = &Bs[cur * 4096];
    s16x8 af[4], bf[4];
#pragma unroll
    for (int m = 0; m < 4; ++m)
      af[m] = *reinterpret_cast<const s16x8*>(&Ab[m * 512 + aro]);
#pragma unroll
    for (int n = 0; n < 4; ++n)
      bf[n] = *reinterpret_cast<const s16x8*>(&Bb[n * 512 + bro]);
#pragma unroll
    for (int m = 0; m < 4; ++m)
#pragma unroll
      for (int n = 0; n < 4; ++n)
        acc[m][n] = __builtin_amdgcn_mfma_f32_16x16x32_bf16(af[m], bf[n], acc[m][n], 0, 0, 0);
    __syncthreads();  // drain after MFMA: next-tile loads had the full phase to land
  }

  // epilogue: C layout col = lane&15, row = kg*4+j (m89-verified); scalar acc reads only
  float sums[4] = {0.f, 0.f, 0.f, 0.f}, sqs[4] = {0.f, 0.f, 0.f, 0.f};
#pragma unroll
  for (int m = 0; m < 4; ++m) {
    int row0 = brow + wr * 64 + m * 16 + kg * 4;
#pragma unroll
    for (int j = 0; j < 4; ++j) {
      int r = row0 + j;
      if (r < M) {
        long rb = (long)r * NOUT;
        long tb = addtab ? (long)ele[r] * NOUT : 0;
#pragma unroll
        for (int n = 0; n < 4; ++n) {
          int col = bcol + wc * 64 + n * 16 + l15;
          float v = acc[m][n][j];
          if (addtab) v += tab[tb + col];
          if (wf32) outf[rb + col] = v;
          else outp[rb + col] = f2b(v);
          sums[n] += v;
          sqs[n] += v * v;
        }
      }
    }
  }
  if (dostats) {
#pragma unroll
    for (int n = 0; n < 4; ++n) {
      sums[n] += __shfl_xor(sums[n], 16);
      sums[n] += __shfl_xor(sums[n], 32);
      sqs[n] += __shfl_xor(sqs[n], 16);
      sqs[n] += __shfl_xor(sqs[n], 32);
    }
    if (kg == 0) {
#pragma unroll
      for (int n = 0; n < 4; ++n) {
        int col = bcol + wc * 64 + n * 16 + l15;
        atomicAdd(&csum[col], sums[n]);
        atomicAdd(&csq[col], sqs[n]);
      }
    }
  }
}

// ---------------- host ----------------
extern "C" void kernel_launch(void* const* d_in, const int* in_sizes, int n_in,
                              void* d_out, int out_size, void* d_ws, size_t ws_size,
                              hipStream_t stream) {
  const float* x    = (const float*)d_in[0];
  const float* dist = (const float*)d_in[1];
  const int* ele    = (const int*)d_in[3];
  const float* l1w  = (const float*)d_in[4];
  const float* l1g  = (const float*)d_in[6];
  const float* l1be = (const float*)d_in[7];
  const float* l2w  = (const float*)d_in[8];
  const float* l2g  = (const float*)d_in[10];
  const float* l2be = (const float*)d_in[11];
  const float* fw   = (const float*)d_in[12];
  const float* fg   = (const float*)d_in[14];
  const float* fbe  = (const float*)d_in[15];

  int N = in_sizes[0] / 1024;  // 100000
  float* out = (float*)d_out;
  u16* xbf = (u16*)d_out;      // bf16 x overlays d_out (exact size, dead by final write)

  int MT = (N + 127) / 128;    // 782

  char* w = (char*)d_ws;
  auto alloc = [&](size_t bytes) {
    char* p = w;
    w += (bytes + 255) & ~(size_t)255;
    return p;
  };
  u16* dist_bf = (u16*)alloc((size_t)N * 256 * 2);
  u16* hp      = (u16*)alloc((size_t)N * NOUT * 2);
  u16* h       = (u16*)alloc((size_t)N * NOUT * 2);
  u16* mean    = (u16*)alloc((size_t)NSEG * NOUT * 2);
  u16* w1bt    = (u16*)alloc((size_t)NOUT * 1280 * 2);
  u16* w2bt    = (u16*)alloc((size_t)NOUT * 1280 * 2);
  u16* fbt     = (u16*)alloc((size_t)NOUT * 1024 * 2);
  float* mc2   = (float*)alloc((size_t)NSEG * NOUT * 4);
  float* mc3   = (float*)alloc((size_t)NSEG * NOUT * 4);
  // ---- contiguous zero-zone: seg_cnt, seg_fill, stats1..3 (single memset) ----
  char* zz0    = w;
  int* seg_cnt = (int*)alloc(NSEG * 4);
  int* seg_fill = (int*)alloc(NSEG * 4);
  float* stats1 = (float*)alloc(NOUT * 2 * 4);  // [sum(512) | sumsq(512)]
  float* stats2 = (float*)alloc(NOUT * 2 * 4);
  float* stats3 = (float*)alloc(NOUT * 2 * 4);
  size_t zzlen = (size_t)(w - zz0);
  int* seg_off = (int*)alloc(NSEG * 4);
  int* rows    = (int*)alloc((size_t)N * 4);

  size_t need = (size_t)(w - (char*)d_ws);
  if (need > ws_size) {
    fprintf(stderr, "kernel_launch: ws too small: need %zu have %zu\n", need, ws_size);
    return;
  }

  long n4x = (long)N * 1024 / 4;
  long n4d = (long)N * 256 / 4;
  long n4h = (long)N * NOUT / 4;
  int gemmGrid = MT * 4;          // 3128
  int mcGrid = (NSEG / 128) * 4;  // 32
  float invM = 1.0f / (float)N;

  // input casts + weight transposes + one zero-zone memset
  k_cast2<<<4096, 256, 0, stream>>>(x, xbf, n4x, dist, dist_bf, n4d);
  dim3 wtg(1280 / 32, NOUT / 32, 3);
  k_wtcastT3<<<wtg, 256, 0, stream>>>(l1w, w1bt, l2w, w2bt, fw, fbt);
  hipMemsetAsync(zz0, 0, zzlen, stream);

  // segment sort
  k_hist<<<512, 256, 0, stream>>>(ele, seg_cnt, N);
  k_scan<<<1, NSEG, 0, stream>>>(seg_cnt, seg_off);
  k_scatter<<<512, 256, 0, stream>>>(ele, seg_off, seg_fill, rows, N);

  // ---- layer 1: A = [x(1024) | dist(256)], K=1280 ----
  k_gemm<1280, 1024, 1280, 0><<<gemmGrid, 256, 0, stream>>>(
      xbf, dist_bf, 1024, 256, 0, 0, ele, w1bt, 1280, mc2, 0,
      hp, mc2, 0, stats1, stats1 + NOUT, 1, N);
  k_bnseg<<<NSEG, 256, 0, stream>>>(hp, h, mean, stats1, l1g, l1be, invM,
                                    seg_off, seg_cnt, rows);

  // ---- layer 2: mc2 = mean @ W2[512:1024); A = [h(512) | dist(256)], K=768 ----
  k_gemm<512, 512, 512, 0><<<mcGrid, 256, 0, stream>>>(
      mean, mean, 512, 512, 0, 0, ele, w2bt + 512, 1280, mc2, 0,
      hp, mc2, 1, stats2, stats2 + NOUT, 0, NSEG);
  k_gemm<768, 512, 512, 512><<<gemmGrid, 256, 0, stream>>>(
      h, dist_bf, 512, 256, 0, 0, ele, w2bt, 1280, mc2, 1,
      hp, mc2, 0, stats2, stats2 + NOUT, 1, N);
  k_bnseg<<<NSEG, 256, 0, stream>>>(hp, h, mean, stats2, l2g, l2be, invM,
                                    seg_off, seg_cnt, rows);

  // ---- final layer: mc3 = mean @ F[512:1024); A = h, K=512 ----
  k_gemm<512, 512, 512, 0><<<mcGrid, 256, 0, stream>>>(
      mean, mean, 512, 512, 0, 0, ele, fbt + 512, 1024, mc3, 0,
      hp, mc3, 1, stats3, stats3 + NOUT, 0, NSEG);
  k_gemm<512, 512, 512, 0><<<gemmGrid, 256, 0, stream>>>(
      h, h, 512, 512, 0, 0, ele, fbt, 1024, mc3, 1,
      hp, mc3, 0, stats3, stats3 + NOUT, 1, N);
  k_final<<<4096, 256, 0, stream>>>(hp, out, stats3, fg, fbe, invM, n4h);
}